// Round 3
// baseline (518.042 us; speedup 1.0000x reference)
//
#include <hip/hip_runtime.h>
#include <math.h>

#define ROWS 64
#define TLEN 64000
#define NFR 251
#define NMELS 80
#define NFB 131072            // big FFT length (>= 2*T-1 -> exact linear conv)
#define PI2F 6.28318530717958647692f

// banked double accumulators:
// 0 S_dt  1 S_rt  2 S_sp  3..6 E0..E3  7 S_mag  8 S_cos  9 S_mel  10 S_c
__device__ double g_part[64][12];
__device__ float2 g_tw1024[1024];   // e^{-2*pi*i*t/1024}, fp64-computed
__device__ float2 g_twf[128];       // e^{-2*pi*i*t/131072}

// slot holding k2 after per-lane radix-4 FFT16 (digit reversal, involution)
__device__ constexpr int DR[16] = {0,4,8,12,1,5,9,13,2,6,10,14,3,7,11,15};
// mirror slot: RM[r] = DR[16 - DR[r]]
__device__ constexpr int RM[16] = {0,3,2,1,15,14,13,12,11,10,9,8,7,6,5,4};

__device__ inline void atomAddD(double* p, double v){
  __hip_atomic_fetch_add(p, v, __ATOMIC_RELAXED, __HIP_MEMORY_SCOPE_AGENT);
}
__device__ inline int brev6(int x){ return (int)((unsigned)__brev((unsigned)x) >> 26); }
__device__ inline float2 cmul(float2 a, float2 b){
  return make_float2(a.x*b.x - a.y*b.y, a.x*b.y + a.y*b.x);
}
__device__ inline float wred(float v){
#pragma unroll
  for (int o = 32; o > 0; o >>= 1) v += __shfl_down(v, o, 64);
  return v;
}

// ---------- per-wave FFT cores ----------
// 64-pt DFT across lanes (one element per lane per slot), radix-2 DIF.
// Output index k1 lives at lane brev6(k1). S=-1 fwd, S=+1 inv (unnormalized).
template<int S, int N>
__device__ inline void fft64_lanes(float2* v, int l){
  float2 W[5];
#pragma unroll
  for (int si = 0; si < 5; ++si){
    int d = 32 >> si;
    float2 w = g_tw1024[(l & (d-1)) * (512/d)];
    if (S > 0) w.y = -w.y;
    W[si] = w;
  }
#pragma unroll
  for (int rr = 0; rr < N; ++rr){
    float2 x = v[rr];
#pragma unroll
    for (int si = 0; si < 6; ++si){
      int d = 32 >> si;
      float tx = __shfl_xor(x.x, d, 64);
      float ty = __shfl_xor(x.y, d, 64);
      bool hi = (l & d) != 0;
      float sx = x.x + tx, sy = x.y + ty;
      float dx = tx - x.x, dy = ty - x.y;
      float rx, ry;
      if (si < 5){ rx = dx*W[si].x - dy*W[si].y; ry = dx*W[si].y + dy*W[si].x; }
      else       { rx = dx; ry = dy; }
      x.x = hi ? rx : sx;
      x.y = hi ? ry : sy;
    }
    v[rr] = x;
  }
}

// per-lane 16-pt FFT, two radix-4 DIF stages, fully unrolled, literal twiddles.
// F[k2] ends up in slot DR[k2].
template<int S>
__device__ inline void fft16_reg(float2* v){
  const float Sf = (float)S;
  const float C1 = 0.9238795325112867f, S1 = 0.3826834323650898f, C2 = 0.7071067811865476f;
  const float2 W1[4] = {{1.f,0.f},{C1,Sf*S1},{C2,Sf*C2},{S1,Sf*C1}};
  const float2 W2[4] = {{1.f,0.f},{C2,Sf*C2},{0.f,Sf},{-C2,Sf*C2}};
  const float2 W3[4] = {{1.f,0.f},{S1,Sf*C1},{-C2,Sf*C2},{-C1,-Sf*S1}};
#pragma unroll
  for (int j = 0; j < 4; ++j){
    float2 x0=v[j], x1=v[j+4], x2=v[j+8], x3=v[j+12];
    float2 t0={x0.x+x2.x, x0.y+x2.y}, t1={x0.x-x2.x, x0.y-x2.y};
    float2 t2={x1.x+x3.x, x1.y+x3.y}, t3={x1.x-x3.x, x1.y-x3.y};
    float2 y0={t0.x+t2.x, t0.y+t2.y};
    float2 y2={t0.x-t2.x, t0.y-t2.y};
    float2 y1={t1.x - Sf*t3.y, t1.y + Sf*t3.x};
    float2 y3={t1.x + Sf*t3.y, t1.y - Sf*t3.x};
    v[j]=y0; v[j+4]=cmul(y1,W1[j]); v[j+8]=cmul(y2,W2[j]); v[j+12]=cmul(y3,W3[j]);
  }
#pragma unroll
  for (int b = 0; b < 4; ++b){
    float2 x0=v[4*b], x1=v[4*b+1], x2=v[4*b+2], x3=v[4*b+3];
    float2 t0={x0.x+x2.x, x0.y+x2.y}, t1={x0.x-x2.x, x0.y-x2.y};
    float2 t2={x1.x+x3.x, x1.y+x3.y}, t3={x1.x-x3.x, x1.y-x3.y};
    v[4*b]   = make_float2(t0.x+t2.x, t0.y+t2.y);
    v[4*b+2] = make_float2(t0.x-t2.x, t0.y-t2.y);
    v[4*b+1] = make_float2(t1.x - Sf*t3.y, t1.y + Sf*t3.x);
    v[4*b+3] = make_float2(t1.x + Sf*t3.y, t1.y - Sf*t3.x);
  }
}

// 1024-pt FFT per wave. Input: v[m] = x[l + 64*m]. Output: slot rr, lane p
// holds X[DR[rr] + 16*brev6(p)].
template<int S>
__device__ inline void fft1024_wave(float2* v, int l){
  fft16_reg<S>(v);
  float2 T = g_tw1024[l]; if (S > 0) T.y = -T.y;
  float2 cur = T;
#pragma unroll
  for (int k2 = 1; k2 < 16; ++k2){
    v[DR[k2]] = cmul(v[DR[k2]], cur);
    if (k2 < 15) cur = cmul(cur, T);
  }
  fft64_lanes<S,16>(v, l);
}

// 128-pt FFT per wave. Input: v[m] = x[l + 64*m], m=0,1. Output: slot rr,
// lane p holds X[rr + 2*brev6(p)].
template<int S>
__device__ inline void fft128_wave(float2* v, int l){
  float2 a = {v[0].x+v[1].x, v[0].y+v[1].y};
  float2 b = {v[0].x-v[1].x, v[0].y-v[1].y};
  float2 T = g_tw1024[8*l]; if (S > 0) T.y = -T.y;
  v[0] = a; v[1] = cmul(b, T);
  fft64_lanes<S,2>(v, l);
}

// ---------------- init: zero accumulators + fp64-accurate twiddle tables ----
extern "C" __global__ void __launch_bounds__(256) k_init(){
  int t = blockIdx.x*256 + threadIdx.x;
  if (t < 768) ((double*)g_part)[t] = 0.0;
  if (t < 1024){
    double a = -2.0*M_PI*(double)t/1024.0;
    g_tw1024[t] = make_float2((float)cos(a), (float)sin(a));
  }
  if (t < 128){
    double a = -2.0*M_PI*(double)t/131072.0;
    g_twf[t] = make_float2((float)cos(a), (float)sin(a));
  }
}

// ---------------- time-domain losses + rir segment energies ----------------
extern "C" __global__ void __launch_bounds__(256) k_time(
    const float* __restrict__ pd, const float* __restrict__ td,
    const float* __restrict__ pr, const float* __restrict__ tr){
  const int NTOT = ROWS*TLEN;
  int stride = gridDim.x * 256;
  float sdt=0.f, srt=0.f, ssp=0.f, e0=0.f, e1=0.f, e2=0.f, e3=0.f;
  for (int i = blockIdx.x*256 + threadIdx.x; i < NTOT; i += stride){
    float d = pd[i] - td[i]; sdt += fabsf(d);
    float p = pr[i];
    float q = p - tr[i];     srt += fabsf(q);
    ssp += fabsf(p);
    int tloc = i % TLEN;
    int seg = tloc / 16000;
    float p2 = p*p;
    if (seg == 0) e0 += p2; else if (seg == 1) e1 += p2;
    else if (seg == 2) e2 += p2; else e3 += p2;
  }
  sdt = wred(sdt); srt = wred(srt); ssp = wred(ssp);
  e0 = wred(e0); e1 = wred(e1); e2 = wred(e2); e3 = wred(e3);
  if ((threadIdx.x & 63) == 0){
    int bank = (blockIdx.x*4 + (threadIdx.x >> 6)) & 63;
    atomAddD(&g_part[bank][0], (double)sdt);
    atomAddD(&g_part[bank][1], (double)srt);
    atomAddD(&g_part[bank][2], (double)ssp);
    atomAddD(&g_part[bank][3], (double)e0);
    atomAddD(&g_part[bank][4], (double)e1);
    atomAddD(&g_part[bank][5], (double)e2);
    atomAddD(&g_part[bank][6], (double)e3);
  }
}

// ---------------- fused STFT (freq + mel) losses, one wave per frame --------
extern "C" __global__ void __launch_bounds__(256) k_stft(
    const float* __restrict__ pd, const float* __restrict__ td){
  __shared__ float2 spec0[4][64];
  __shared__ float pp[4][516], tt[4][516];
  int wid = threadIdx.x >> 6, l = threadIdx.x & 63;
  int frame = blockIdx.x*4 + wid;
  int r = frame / NFR, fr = frame - r*NFR;
  const float* pdr = pd + (size_t)r*TLEN;
  const float* tdr = td + (size_t)r*TLEN;
  int base = fr*256 - 512;
  float2 v[16];
#pragma unroll
  for (int m = 0; m < 16; ++m){
    int j = l + 64*m;
    int g = base + j;
    g = (g < 0) ? -g : ((g >= TLEN) ? (2*TLEN - 2 - g) : g);
    float w = 0.5f - 0.5f*__cosf((PI2F/1024.0f)*(float)j);   // periodic hann
    v[m] = make_float2(pdr[g]*w, tdr[g]*w);
  }
  fft1024_wave<-1>(v, l);
  const float scale = 0.05103103630798288f;   // 1/sqrt(384)
#pragma unroll
  for (int m = 0; m < 16; ++m){ v[m].x *= scale; v[m].y *= scale; }
  int kb = brev6(l);
  spec0[wid][kb] = v[0];          // the k2=0 line: Z[16*k1] at index k1
  float magp = 0.f, cosp = 0.f;
  // k2 = 1..15 lines: mirror of (slot rr, lane l) is (slot RM[rr], lane 63-l).
  // Each unordered (k, 1024-k) pair enumerated twice -> weight 0.5.
#pragma unroll
  for (int rr = 1; rr < 16; ++rr){
    float2 z = v[rr];
    float2 zm;
    zm.x = __shfl(v[RM[rr]].x, 63 - l, 64);
    zm.y = __shfl(v[RM[rr]].y, 63 - l, 64);
    int k = DR[rr] + 16*kb;
    float px = 0.5f*(z.x + zm.x), py = 0.5f*(z.y - zm.y);
    float tx = 0.5f*(z.y + zm.y), ty = -0.5f*(z.x - zm.x);
    float ppk = px*px + py*py, ttk = tx*tx + ty*ty;
    magp += 0.5f*fabsf(sqrtf(ppk) - sqrtf(ttk));
    float den = ppk*ttk;
    cosp += 0.5f*((den > 0.f) ? (px*tx + py*ty)*rsqrtf(den) : 1.0f);
    int kk = (k <= 512) ? k : 1024 - k;
    pp[wid][kk] = ppk; tt[wid][kk] = ttk;   // both writers write identical bits
  }
  if (l <= 32){                    // k = 16*l, weight 1
    float2 z  = spec0[wid][l];
    float2 zm = spec0[wid][(64 - l) & 63];
    float px = 0.5f*(z.x + zm.x), py = 0.5f*(z.y - zm.y);
    float tx = 0.5f*(z.y + zm.y), ty = -0.5f*(z.x - zm.x);
    float ppk = px*px + py*py, ttk = tx*tx + ty*ty;
    magp += fabsf(sqrtf(ppk) - sqrtf(ttk));
    float den = ppk*ttk;
    cosp += (den > 0.f) ? (px*tx + py*ty)*rsqrtf(den) : 1.0f;
    pp[wid][16*l] = ppk; tt[wid][16*l] = ttk;
  }
  // mel (same-wave LDS: program order guarantees pp/tt visible)
  float melp = 0.f;
  const float maxmel = 2595.0f * log10f(1.0f + 8000.0f/700.0f);
#pragma unroll
  for (int pass = 0; pass < 2; ++pass){
    int m = l + 64*pass;
    if (m < NMELS){
      float f0 = 700.0f*(exp10f(maxmel*(float)(m  ) * (1.0f/81.0f) * (1.0f/2595.0f)) - 1.0f);
      float f1 = 700.0f*(exp10f(maxmel*(float)(m+1) * (1.0f/81.0f) * (1.0f/2595.0f)) - 1.0f);
      float f2 = 700.0f*(exp10f(maxmel*(float)(m+2) * (1.0f/81.0f) * (1.0f/2595.0f)) - 1.0f);
      float i1 = 1.0f/(f1 - f0), i2 = 1.0f/(f2 - f1);
      const float df = 15.625f;
      int lo = (int)ceilf(f0 * (1.0f/df));  if (lo < 0) lo = 0;
      int hi = (int)floorf(f2 * (1.0f/df)); if (hi > 512) hi = 512;
      float pm = 0.f, tm = 0.f;
      for (int k = lo; k <= hi; ++k){
        float frq = df*(float)k;
        float c = fminf((frq - f0)*i1, (f2 - frq)*i2);
        c = fmaxf(c, 0.f);
        pm += c*pp[wid][k]; tm += c*tt[wid][k];
      }
      melp += fabsf(logf(pm + 1e-8f) - logf(tm + 1e-8f));
    }
  }
  float m1 = wred(magp), m2 = wred(cosp), m3 = wred(melp);
  if (l == 0){
    int bank = (blockIdx.x*4 + wid) & 63;
    atomAddD(&g_part[bank][7], (double)m1);
    atomAddD(&g_part[bank][8], (double)m2);
    atomAddD(&g_part[bank][9], (double)m3);
  }
}

// ---------------- consistency: four-step FFT of 131072 = 128 x 1024 ---------
// n = n1 + 128*n2 ; k = k2 + 1024*k1 ; buf layout [k2*128 + k1] (and [k2*128+n1])
// fwd1: per n1, 1024-pt FFT over n2, * W_NFB^{n1*k2}, store transposed
extern "C" __global__ void __launch_bounds__(256) k_fwd1(
    const float* __restrict__ pd, const float* __restrict__ pr,
    float2* __restrict__ buf, int row0){
  int wid = threadIdx.x >> 6, l = threadIdx.x & 63;
  int rl = blockIdx.y;
  int n1 = blockIdx.x*4 + wid;
  const float* a = pd + (size_t)(row0+rl)*TLEN;
  const float* b = pr + (size_t)(row0+rl)*TLEN;
  float2 v[16];
#pragma unroll
  for (int m = 0; m < 16; ++m){
    int n2 = l + 64*m;
    if (n2 < 500){ int n = n1 + 128*n2; v[m] = make_float2(a[n], b[n]); }
    else v[m] = make_float2(0.f, 0.f);
  }
  fft1024_wave<-1>(v, l);
  float2* rowp = buf + (size_t)rl*NFB;
  int kb = brev6(l);
#pragma unroll
  for (int rr = 0; rr < 16; ++rr){
    int K = DR[rr] + 16*kb;
    unsigned idx = (unsigned)n1 * (unsigned)K;         // < 131072
    float2 W = cmul(g_tw1024[idx >> 7], g_twf[idx & 127]);
    rowp[(size_t)K*128 + n1] = cmul(v[rr], W);
  }
}

// fwd2: per k2, 128-pt FFT over n1 (contiguous 1 KB row), in place
extern "C" __global__ void __launch_bounds__(256) k_fwd2(float2* __restrict__ buf){
  int wid = threadIdx.x >> 6, l = threadIdx.x & 63;
  int K = blockIdx.x*4 + wid;
  float2* rowp = buf + (size_t)blockIdx.y*NFB + (size_t)K*128;
  float2 v[2] = { rowp[l], rowp[l+64] };
  fft128_wave<-1>(v, l);
  int kb = brev6(l);
  rowp[2*kb]   = v[0];
  rowp[2*kb+1] = v[1];
}

// pointwise: split packed spectrum Z into D,R; C = D*R (unchanged)
extern "C" __global__ void __launch_bounds__(256) k_point(float2* __restrict__ buf){
  int rl = blockIdx.y;
  int t = blockIdx.x*256 + threadIdx.x;   // 0..65535
  int k2 = t >> 6, k1 = t & 63;
  float2* rowp = buf + (size_t)rl*NFB;
  if (k2 == 0){
    if (k1 == 0){
      float2 z0 = rowp[0];  rowp[0]  = make_float2(z0.x*z0.y, 0.f);   // k=0
      float2 zh = rowp[64]; rowp[64] = make_float2(zh.x*zh.y, 0.f);   // k=NF/2
    } else {
      float2 z = rowp[k1], zm = rowp[128 - k1];
      float Dx = 0.5f*(z.x + zm.x), Dy = 0.5f*(z.y - zm.y);
      float Rx = 0.5f*(z.y + zm.y), Ry = -0.5f*(z.x - zm.x);
      float Cx = Dx*Rx - Dy*Ry, Cy = Dx*Ry + Dy*Rx;
      rowp[k1]       = make_float2(Cx,  Cy);
      rowp[128 - k1] = make_float2(Cx, -Cy);
    }
  } else {
    int a  = k2*128 + k1;
    int am = (1024 - k2)*128 + (127 - k1);
    float2 z = rowp[a], zm = rowp[am];
    float Dx = 0.5f*(z.x + zm.x), Dy = 0.5f*(z.y - zm.y);
    float Rx = 0.5f*(z.y + zm.y), Ry = -0.5f*(z.x - zm.x);
    float Cx = Dx*Rx - Dy*Ry, Cy = Dx*Ry + Dy*Rx;
    rowp[a]  = make_float2(Cx,  Cy);
    rowp[am] = make_float2(Cx, -Cy);
  }
}

// inv1: per k2, inverse 128-pt FFT over k1, * conj(W_NFB^{n1*k2}), in place
extern "C" __global__ void __launch_bounds__(256) k_inv1(float2* __restrict__ buf){
  int wid = threadIdx.x >> 6, l = threadIdx.x & 63;
  int k2 = blockIdx.x*4 + wid;
  float2* rowp = buf + (size_t)blockIdx.y*NFB + (size_t)k2*128;
  float2 v[2] = { rowp[l], rowp[l+64] };
  fft128_wave<1>(v, l);
  int kb = brev6(l);
#pragma unroll
  for (int rr = 0; rr < 2; ++rr){
    int n1 = rr + 2*kb;
    unsigned idx = (unsigned)n1 * (unsigned)k2;        // < 131072
    float2 W = cmul(g_tw1024[idx >> 7], g_twf[idx & 127]);
    W.y = -W.y;                                        // conjugate
    rowp[n1] = cmul(v[rr], W);
  }
}

// inv2: per n1, inverse 1024-pt FFT over k2; fused |rec - mix| reduction
extern "C" __global__ void __launch_bounds__(256) k_inv2(
    const float* __restrict__ mix, float2* __restrict__ buf, int row0){
  int wid = threadIdx.x >> 6, l = threadIdx.x & 63;
  int rl = blockIdx.y;
  int n1 = blockIdx.x*4 + wid;
  float2* rowp = buf + (size_t)rl*NFB;
  float2 v[16];
#pragma unroll
  for (int m = 0; m < 16; ++m)
    v[m] = rowp[(size_t)(l + 64*m)*128 + n1];
  fft1024_wave<1>(v, l);
  const float* mr = mix + (size_t)(row0+rl)*TLEN;
  const float invn = 1.0f/(float)NFB;
  float acc = 0.f;
  int kb = brev6(l);
#pragma unroll
  for (int rr = 0; rr < 16; ++rr){
    int n2 = DR[rr] + 16*kb;
    if (n2 < 500){
      int n = n1 + 128*n2;
      acc += fabsf(v[rr].x*invn - mr[n]);
    }
  }
  acc = wred(acc);
  if (l == 0){
    int bank = (blockIdx.x*4 + wid + blockIdx.y*16) & 63;
    atomAddD(&g_part[bank][10], (double)acc);
  }
}

// ---------------- combine ----------------
extern "C" __global__ void __launch_bounds__(64) k_finalize(float* __restrict__ out){
  __shared__ double s[12];
  int t = threadIdx.x;
  if (t < 12){
    double v = 0.0;
    for (int b = 0; b < 64; ++b) v += g_part[b][t];
    s[t] = v;
  }
  __syncthreads();
  if (t == 0){
    double dt = s[0] / 4096000.0;
    double rt = s[1] / 4096000.0;
    double sp = s[2] / 4096000.0;
    double e0 = s[3] / 1024000.0, e1 = s[4] / 1024000.0;
    double e2 = s[5] / 1024000.0, e3 = s[6] / 1024000.0;
    double dec = fmax(e1 - 0.8*e0, 0.0) + fmax(e2 - 0.8*e1, 0.0) + fmax(e3 - 0.8*e2, 0.0);
    double c1 = 8240832.0;              // 64*513*251
    double freq = s[7]/c1 + 0.1*(1.0 - s[8]/c1);
    double mel  = s[9] / 1285120.0;     // 64*80*251
    double cons = s[10] / 4096000.0;
    double total = 3.0*(dt + 0.5*freq + 0.3*mel)
                 + (rt + 0.1*(sp + dec))
                 + 0.2*cons;
    out[0] = (float)total;
  }
}

extern "C" void kernel_launch(void* const* d_in, const int* in_sizes, int n_in,
                              void* d_out, int out_size, void* d_ws, size_t ws_size,
                              hipStream_t stream){
  const float* pd = (const float*)d_in[0];
  const float* pr = (const float*)d_in[1];
  const float* td = (const float*)d_in[2];
  const float* tr = (const float*)d_in[3];
  const float* mx = (const float*)d_in[4];
  float* out = (float*)d_out;
  float2* buf = (float2*)d_ws;

  size_t rowBytes = (size_t)NFB * sizeof(float2);     // 1 MiB per row
  int maxrows = (int)(ws_size / rowBytes);
  if (maxrows > ROWS) maxrows = ROWS;
  if (maxrows < 1) maxrows = 1;

  hipLaunchKernelGGL(k_init, dim3(4), dim3(256), 0, stream);
  hipLaunchKernelGGL(k_time, dim3(2048), dim3(256), 0, stream, pd, td, pr, tr);
  hipLaunchKernelGGL(k_stft, dim3(ROWS*NFR/4), dim3(256), 0, stream, pd, td);
  for (int row0 = 0; row0 < ROWS; row0 += maxrows){
    int nr = ROWS - row0; if (nr > maxrows) nr = maxrows;
    hipLaunchKernelGGL(k_fwd1,  dim3(32, nr),  dim3(256), 0, stream, pd, pr, buf, row0);
    hipLaunchKernelGGL(k_fwd2,  dim3(256, nr), dim3(256), 0, stream, buf);
    hipLaunchKernelGGL(k_point, dim3(256, nr), dim3(256), 0, stream, buf);
    hipLaunchKernelGGL(k_inv1,  dim3(256, nr), dim3(256), 0, stream, buf);
    hipLaunchKernelGGL(k_inv2,  dim3(32, nr),  dim3(256), 0, stream, mx, buf, row0);
  }
  hipLaunchKernelGGL(k_finalize, dim3(1), dim3(64), 0, stream, out);
}

// Round 4
// 435.656 us; speedup vs baseline: 1.1891x; 1.1891x over previous
//
#include <hip/hip_runtime.h>
#include <math.h>

#define ROWS 64
#define TLEN 64000
#define NFR 251
#define NMELS 80
#define NFB 131072            // big FFT length (>= 2*T-1 -> exact linear conv)
#define PI2F 6.28318530717958647692f

// banked double accumulators:
// 0 S_dt  1 S_rt  2 S_sp  3..6 E0..E3  7 S_mag  8 S_cos  9 S_mel  10 S_c
__device__ double g_part[64][12];
__device__ float2 g_tw1024[1024];   // e^{-2*pi*i*t/1024}, fp64-computed
__device__ float2 g_twf[128];       // e^{-2*pi*i*t/131072}

// slot holding k2 after per-lane radix-4 FFT16 (digit reversal, involution)
__device__ constexpr int DR[16] = {0,4,8,12,1,5,9,13,2,6,10,14,3,7,11,15};
// mirror slot: RM[r] = DR[16 - DR[r]]
__device__ constexpr int RM[16] = {0,3,2,1,15,14,13,12,11,10,9,8,7,6,5,4};

__device__ inline int dr4(int i){ return ((i & 3) << 2) | (i >> 2); }  // DR, runtime

__device__ inline void atomAddD(double* p, double v){
  __hip_atomic_fetch_add(p, v, __ATOMIC_RELAXED, __HIP_MEMORY_SCOPE_AGENT);
}
__device__ inline int brev6(int x){ return (int)((unsigned)__brev((unsigned)x) >> 26); }
__device__ inline float2 cmul(float2 a, float2 b){
  return make_float2(a.x*b.x - a.y*b.y, a.x*b.y + a.y*b.x);
}
__device__ inline float wred(float v){
#pragma unroll
  for (int o = 32; o > 0; o >>= 1) v += __shfl_down(v, o, 64);
  return v;
}

// ---------- per-wave FFT cores (forward DIF: natural in, bit-reversed out) ----------
template<int S, int N>
__device__ inline void fft64_lanes(float2* v, int l){
  float2 W[5];
#pragma unroll
  for (int si = 0; si < 5; ++si){
    int d = 32 >> si;
    float2 w = g_tw1024[(l & (d-1)) * (512/d)];
    if (S > 0) w.y = -w.y;
    W[si] = w;
  }
#pragma unroll
  for (int rr = 0; rr < N; ++rr){
    float2 x = v[rr];
#pragma unroll
    for (int si = 0; si < 6; ++si){
      int d = 32 >> si;
      float tx = __shfl_xor(x.x, d, 64);
      float ty = __shfl_xor(x.y, d, 64);
      bool hi = (l & d) != 0;
      float sx = x.x + tx, sy = x.y + ty;
      float dx = tx - x.x, dy = ty - x.y;
      float rx, ry;
      if (si < 5){ rx = dx*W[si].x - dy*W[si].y; ry = dx*W[si].y + dy*W[si].x; }
      else       { rx = dx; ry = dy; }
      x.x = hi ? rx : sx;
      x.y = hi ? ry : sy;
    }
    v[rr] = x;
  }
}

template<int S>
__device__ inline void fft16_reg(float2* v){
  const float Sf = (float)S;
  const float C1 = 0.9238795325112867f, S1 = 0.3826834323650898f, C2 = 0.7071067811865476f;
  const float2 W1[4] = {{1.f,0.f},{C1,Sf*S1},{C2,Sf*C2},{S1,Sf*C1}};
  const float2 W2[4] = {{1.f,0.f},{C2,Sf*C2},{0.f,Sf},{-C2,Sf*C2}};
  const float2 W3[4] = {{1.f,0.f},{S1,Sf*C1},{-C2,Sf*C2},{-C1,-Sf*S1}};
#pragma unroll
  for (int j = 0; j < 4; ++j){
    float2 x0=v[j], x1=v[j+4], x2=v[j+8], x3=v[j+12];
    float2 t0={x0.x+x2.x, x0.y+x2.y}, t1={x0.x-x2.x, x0.y-x2.y};
    float2 t2={x1.x+x3.x, x1.y+x3.y}, t3={x1.x-x3.x, x1.y-x3.y};
    float2 y0={t0.x+t2.x, t0.y+t2.y};
    float2 y2={t0.x-t2.x, t0.y-t2.y};
    float2 y1={t1.x - Sf*t3.y, t1.y + Sf*t3.x};
    float2 y3={t1.x + Sf*t3.y, t1.y - Sf*t3.x};
    v[j]=y0; v[j+4]=cmul(y1,W1[j]); v[j+8]=cmul(y2,W2[j]); v[j+12]=cmul(y3,W3[j]);
  }
#pragma unroll
  for (int b = 0; b < 4; ++b){
    float2 x0=v[4*b], x1=v[4*b+1], x2=v[4*b+2], x3=v[4*b+3];
    float2 t0={x0.x+x2.x, x0.y+x2.y}, t1={x0.x-x2.x, x0.y-x2.y};
    float2 t2={x1.x+x3.x, x1.y+x3.y}, t3={x1.x-x3.x, x1.y-x3.y};
    v[4*b]   = make_float2(t0.x+t2.x, t0.y+t2.y);
    v[4*b+2] = make_float2(t0.x-t2.x, t0.y-t2.y);
    v[4*b+1] = make_float2(t1.x - Sf*t3.y, t1.y + Sf*t3.x);
    v[4*b+3] = make_float2(t1.x + Sf*t3.y, t1.y - Sf*t3.x);
  }
}

// 1024-pt forward: input v[m]=x[l+64m]; output slot rr, lane l = X[DR[rr]+16*brev6(l)]
template<int S>
__device__ inline void fft1024_wave(float2* v, int l){
  fft16_reg<S>(v);
  float2 T = g_tw1024[l]; if (S > 0) T.y = -T.y;
  float2 cur = T;
#pragma unroll
  for (int k2 = 1; k2 < 16; ++k2){
    v[DR[k2]] = cmul(v[DR[k2]], cur);
    if (k2 < 15) cur = cmul(cur, T);
  }
  fft64_lanes<S,16>(v, l);
}

// 128-pt forward: input v[m]=x[l+64m]; output slot rr, lane l = X[rr+2*brev6(l)]
template<int S>
__device__ inline void fft128_wave(float2* v, int l){
  float2 a = {v[0].x+v[1].x, v[0].y+v[1].y};
  float2 b = {v[0].x-v[1].x, v[0].y-v[1].y};
  float2 T = g_tw1024[8*l]; if (S > 0) T.y = -T.y;
  v[0] = a; v[1] = cmul(b, T);
  fft64_lanes<S,2>(v, l);
}

// ---------- adjoint (DIT) inverses: bit-reversed in, natural out, unnormalized ----------
template<int N>
__device__ inline void ifft64_lanes(float2* v, int l){
  float2 W[5];
#pragma unroll
  for (int si = 0; si < 5; ++si){
    int d = 32 >> si;
    float2 w = g_tw1024[(l & (d-1)) * (512/d)];
    w.y = -w.y;                       // conj of forward(-1) twiddle
    W[si] = w;
  }
#pragma unroll
  for (int rr = 0; rr < N; ++rr){
    float2 x = v[rr];
#pragma unroll
    for (int si = 5; si >= 0; --si){
      int d = 32 >> si;
      bool hi = (l & d) != 0;
      float2 xp = x;
      if (si < 5 && hi) xp = cmul(x, W[si]);
      float tx = __shfl_xor(xp.x, d, 64);
      float ty = __shfl_xor(xp.y, d, 64);
      x.x = hi ? (tx - xp.x) : (xp.x + tx);
      x.y = hi ? (ty - xp.y) : (xp.y + ty);
    }
    v[rr] = x;
  }
}

__device__ inline void r4p(float2* v, int i0, int i1, int i2, int i3){
  // radix-4 DFT, sign +1, in place
  float2 x0=v[i0], x1=v[i1], x2=v[i2], x3=v[i3];
  float2 t0={x0.x+x2.x, x0.y+x2.y}, t1={x0.x-x2.x, x0.y-x2.y};
  float2 t2={x1.x+x3.x, x1.y+x3.y}, t3={x1.x-x3.x, x1.y-x3.y};
  v[i0] = make_float2(t0.x+t2.x, t0.y+t2.y);
  v[i2] = make_float2(t0.x-t2.x, t0.y-t2.y);
  v[i1] = make_float2(t1.x - t3.y, t1.y + t3.x);
  v[i3] = make_float2(t1.x + t3.y, t1.y - t3.x);
}

// adjoint of fft16_reg<-1>: DR-ordered input -> natural m output (x16 unnorm)
__device__ inline void ifft16_reg(float2* v){
#pragma unroll
  for (int b = 0; b < 4; ++b) r4p(v, 4*b, 4*b+1, 4*b+2, 4*b+3);
  const float C1 = 0.9238795325112867f, S1 = 0.3826834323650898f, C2 = 0.7071067811865476f;
  const float2 W1[4] = {{1.f,0.f},{C1,S1},{C2,C2},{S1,C1}};
  const float2 W2[4] = {{1.f,0.f},{C2,C2},{0.f,1.f},{-C2,C2}};
  const float2 W3[4] = {{1.f,0.f},{S1,C1},{-C2,C2},{-C1,-S1}};
#pragma unroll
  for (int j = 1; j < 4; ++j){
    v[j+4]  = cmul(v[j+4],  W1[j]);
    v[j+8]  = cmul(v[j+8],  W2[j]);
    v[j+12] = cmul(v[j+12], W3[j]);
  }
#pragma unroll
  for (int j = 0; j < 4; ++j) r4p(v, j, j+4, j+8, j+12);
}

// input slot rr, lane l = X[rr+2*brev6(l)]; output v[m], lane l = 128*x[l+64m]
__device__ inline void ifft128_wave(float2* v, int l){
  ifft64_lanes<2>(v, l);
  float2 T = g_tw1024[8*l]; T.y = -T.y;
  v[1] = cmul(v[1], T);
  float2 a = {v[0].x+v[1].x, v[0].y+v[1].y};
  float2 b = {v[0].x-v[1].x, v[0].y-v[1].y};
  v[0] = a; v[1] = b;
}

// input slot rr, lane l = X[DR[rr]+16*brev6(l)]; output v[m], lane l = 1024*x[l+64m]
__device__ inline void ifft1024_wave(float2* v, int l){
  ifft64_lanes<16>(v, l);
  float2 T = g_tw1024[l]; T.y = -T.y;
  float2 cur = T;
#pragma unroll
  for (int k2 = 1; k2 < 16; ++k2){
    v[DR[k2]] = cmul(v[DR[k2]], cur);
    if (k2 < 15) cur = cmul(cur, T);
  }
  ifft16_reg(v);
}

// ---------------- init: zero accumulators + fp64-accurate twiddle tables ----
extern "C" __global__ void __launch_bounds__(256) k_init(){
  int t = blockIdx.x*256 + threadIdx.x;
  if (t < 768) ((double*)g_part)[t] = 0.0;
  if (t < 1024){
    double a = -2.0*M_PI*(double)t/1024.0;
    g_tw1024[t] = make_float2((float)cos(a), (float)sin(a));
  }
  if (t < 128){
    double a = -2.0*M_PI*(double)t/131072.0;
    g_twf[t] = make_float2((float)cos(a), (float)sin(a));
  }
}

// ---------------- time-domain losses + rir segment energies ----------------
extern "C" __global__ void __launch_bounds__(256) k_time(
    const float* __restrict__ pd, const float* __restrict__ td,
    const float* __restrict__ pr, const float* __restrict__ tr){
  const int NTOT = ROWS*TLEN;
  int stride = gridDim.x * 256;
  float sdt=0.f, srt=0.f, ssp=0.f, e0=0.f, e1=0.f, e2=0.f, e3=0.f;
  for (int i = blockIdx.x*256 + threadIdx.x; i < NTOT; i += stride){
    float d = pd[i] - td[i]; sdt += fabsf(d);
    float p = pr[i];
    float q = p - tr[i];     srt += fabsf(q);
    ssp += fabsf(p);
    int tloc = i % TLEN;
    int seg = tloc / 16000;
    float p2 = p*p;
    if (seg == 0) e0 += p2; else if (seg == 1) e1 += p2;
    else if (seg == 2) e2 += p2; else e3 += p2;
  }
  sdt = wred(sdt); srt = wred(srt); ssp = wred(ssp);
  e0 = wred(e0); e1 = wred(e1); e2 = wred(e2); e3 = wred(e3);
  if ((threadIdx.x & 63) == 0){
    int bank = (blockIdx.x*4 + (threadIdx.x >> 6)) & 63;
    atomAddD(&g_part[bank][0], (double)sdt);
    atomAddD(&g_part[bank][1], (double)srt);
    atomAddD(&g_part[bank][2], (double)ssp);
    atomAddD(&g_part[bank][3], (double)e0);
    atomAddD(&g_part[bank][4], (double)e1);
    atomAddD(&g_part[bank][5], (double)e2);
    atomAddD(&g_part[bank][6], (double)e3);
  }
}

// ---------------- fused STFT (freq + mel) losses, one wave per frame --------
extern "C" __global__ void __launch_bounds__(256) k_stft(
    const float* __restrict__ pd, const float* __restrict__ td){
  __shared__ float2 spec0[4][64];
  __shared__ float pp[4][516], tt[4][516];
  int wid = threadIdx.x >> 6, l = threadIdx.x & 63;
  int frame = blockIdx.x*4 + wid;
  int r = frame / NFR, fr = frame - r*NFR;
  const float* pdr = pd + (size_t)r*TLEN;
  const float* tdr = td + (size_t)r*TLEN;
  int base = fr*256 - 512;
  float2 v[16];
#pragma unroll
  for (int m = 0; m < 16; ++m){
    int j = l + 64*m;
    int g = base + j;
    g = (g < 0) ? -g : ((g >= TLEN) ? (2*TLEN - 2 - g) : g);
    float w = 0.5f - 0.5f*__cosf((PI2F/1024.0f)*(float)j);   // periodic hann
    v[m] = make_float2(pdr[g]*w, tdr[g]*w);
  }
  fft1024_wave<-1>(v, l);
  const float scale = 0.05103103630798288f;   // 1/sqrt(384)
#pragma unroll
  for (int m = 0; m < 16; ++m){ v[m].x *= scale; v[m].y *= scale; }
  int kb = brev6(l);
  spec0[wid][kb] = v[0];          // the k2=0 line: Z[16*k1] at index k1
  float magp = 0.f, cosp = 0.f;
#pragma unroll
  for (int rr = 1; rr < 16; ++rr){
    float2 z = v[rr];
    float2 zm;
    zm.x = __shfl(v[RM[rr]].x, 63 - l, 64);
    zm.y = __shfl(v[RM[rr]].y, 63 - l, 64);
    int k = DR[rr] + 16*kb;
    float px = 0.5f*(z.x + zm.x), py = 0.5f*(z.y - zm.y);
    float tx = 0.5f*(z.y + zm.y), ty = -0.5f*(z.x - zm.x);
    float ppk = px*px + py*py, ttk = tx*tx + ty*ty;
    magp += 0.5f*fabsf(sqrtf(ppk) - sqrtf(ttk));
    float den = ppk*ttk;
    cosp += 0.5f*((den > 0.f) ? (px*tx + py*ty)*rsqrtf(den) : 1.0f);
    int kk = (k <= 512) ? k : 1024 - k;
    pp[wid][kk] = ppk; tt[wid][kk] = ttk;
  }
  if (l <= 32){                    // k = 16*l, weight 1
    float2 z  = spec0[wid][l];
    float2 zm = spec0[wid][(64 - l) & 63];
    float px = 0.5f*(z.x + zm.x), py = 0.5f*(z.y - zm.y);
    float tx = 0.5f*(z.y + zm.y), ty = -0.5f*(z.x - zm.x);
    float ppk = px*px + py*py, ttk = tx*tx + ty*ty;
    magp += fabsf(sqrtf(ppk) - sqrtf(ttk));
    float den = ppk*ttk;
    cosp += (den > 0.f) ? (px*tx + py*ty)*rsqrtf(den) : 1.0f;
    pp[wid][16*l] = ppk; tt[wid][16*l] = ttk;
  }
  float melp = 0.f;
  const float maxmel = 2595.0f * log10f(1.0f + 8000.0f/700.0f);
#pragma unroll
  for (int pass = 0; pass < 2; ++pass){
    int m = l + 64*pass;
    if (m < NMELS){
      float f0 = 700.0f*(exp10f(maxmel*(float)(m  ) * (1.0f/81.0f) * (1.0f/2595.0f)) - 1.0f);
      float f1 = 700.0f*(exp10f(maxmel*(float)(m+1) * (1.0f/81.0f) * (1.0f/2595.0f)) - 1.0f);
      float f2 = 700.0f*(exp10f(maxmel*(float)(m+2) * (1.0f/81.0f) * (1.0f/2595.0f)) - 1.0f);
      float i1 = 1.0f/(f1 - f0), i2 = 1.0f/(f2 - f1);
      const float df = 15.625f;
      int lo = (int)ceilf(f0 * (1.0f/df));  if (lo < 0) lo = 0;
      int hi = (int)floorf(f2 * (1.0f/df)); if (hi > 512) hi = 512;
      float pm = 0.f, tm = 0.f;
      for (int k = lo; k <= hi; ++k){
        float frq = df*(float)k;
        float c = fminf((frq - f0)*i1, (f2 - frq)*i2);
        c = fmaxf(c, 0.f);
        pm += c*pp[wid][k]; tm += c*tt[wid][k];
      }
      melp += fabsf(logf(pm + 1e-8f) - logf(tm + 1e-8f));
    }
  }
  float m1 = wred(magp), m2 = wred(cosp), m3 = wred(melp);
  if (l == 0){
    int bank = (blockIdx.x*4 + wid) & 63;
    atomAddD(&g_part[bank][7], (double)m1);
    atomAddD(&g_part[bank][8], (double)m2);
    atomAddD(&g_part[bank][9], (double)m3);
  }
}

// ---------------- consistency: four-step FFT of 131072 = 128 x 1024 ---------
// n = n1 + 128*n2 ; k = K + 1024*k1 (K in [0,1024)).
// buf layout: [s][n1], s = rr*64 + l  (register-natural; K = DR[rr>>?]... K = perm(s))
// fwd1: per n1, 1024-pt FFT over n2, * W_NFB^{n1*K}, store register-natural
extern "C" __global__ void __launch_bounds__(512) k_fwd1(
    const float* __restrict__ pd, const float* __restrict__ pr,
    float2* __restrict__ buf, int row0){
  int wid = threadIdx.x >> 6, l = threadIdx.x & 63;
  int rl = blockIdx.y;
  int n1 = blockIdx.x*8 + wid;          // 8 adjacent n1 per block -> line-coherent stores
  const float* a = pd + (size_t)(row0+rl)*TLEN;
  const float* b = pr + (size_t)(row0+rl)*TLEN;
  float2 v[16];
#pragma unroll
  for (int m = 0; m < 16; ++m){
    int n2 = l + 64*m;
    if (n2 < 500){ int n = n1 + 128*n2; v[m] = make_float2(a[n], b[n]); }
    else v[m] = make_float2(0.f, 0.f);
  }
  fft1024_wave<-1>(v, l);
  float2* rowp = buf + (size_t)rl*NFB;
  int kb = brev6(l);
#pragma unroll
  for (int rr = 0; rr < 16; ++rr){
    int K = DR[rr] + 16*kb;
    unsigned idx = (unsigned)n1 * (unsigned)K;         // < 131072
    float2 W = cmul(g_tw1024[idx >> 7], g_twf[idx & 127]);
    rowp[(size_t)(rr*64 + l)*128 + n1] = cmul(v[rr], W);
  }
}

// D/R split + product for one element (z) given its mirror partner (zm)
__device__ inline float2 pointmul(float2 z, float2 zm){
  float Dx = 0.5f*(z.x + zm.x), Dy = 0.5f*(z.y - zm.y);
  float Rx = 0.5f*(z.y + zm.y), Ry = -0.5f*(z.x - zm.x);
  return make_float2(Dx*Rx - Dy*Ry, Dx*Ry + Dy*Rx);
}

// k_mid: fused fwd2 + pointwise + inv1. One wave per conjugate row pair.
extern "C" __global__ void __launch_bounds__(256) k_mid(float2* __restrict__ buf){
  int wid = threadIdx.x >> 6, l = threadIdx.x & 63;
  int p = blockIdx.x*4 + wid;           // pair id = k2 of row A, 0..512
  if (p > 512) return;
  int k2A = p, k2B = (1024 - p) & 1023;
  int sA = dr4(k2A & 15)*64 + brev6(k2A >> 4);
  int sB = dr4(k2B & 15)*64 + brev6(k2B >> 4);
  float2* base = buf + (size_t)blockIdx.y*NFB;
  float2* rA = base + (size_t)sA*128;
  float2* rB = base + (size_t)sB*128;
  bool pair = (sB != sA);
  float2 vA[2] = { rA[l], rA[l+64] };
  float2 vB[2];
  if (pair){ vB[0] = rB[l]; vB[1] = rB[l+64]; }
  fft128_wave<-1>(vA, l);
  if (pair) fft128_wave<-1>(vB, l);
  int lx = l ^ 63;
  float2 cA[2];
  if (p == 0){
    // self row k2=0: element k1=rr+2kb mirrors to (rr, kb'=-kb mod 64) for rr=0,
    // (1, 63-kb) for rr=1
    int kb = brev6(l);
    int q0 = brev6((64 - kb) & 63);
    float2 zm0 = { __shfl(vA[0].x, q0, 64), __shfl(vA[0].y, q0, 64) };
    float2 zm1 = { __shfl(vA[1].x, lx, 64), __shfl(vA[1].y, lx, 64) };
    cA[0] = pointmul(vA[0], zm0);
    cA[1] = pointmul(vA[1], zm1);
  } else {
    const float2* src = pair ? vB : vA;   // p==512 self-pairs within its own row
    float2 zm0 = { __shfl(src[1].x, lx, 64), __shfl(src[1].y, lx, 64) };
    float2 zm1 = { __shfl(src[0].x, lx, 64), __shfl(src[0].y, lx, 64) };
    cA[0] = pointmul(vA[0], zm0);
    cA[1] = pointmul(vA[1], zm1);
  }
  float2 cB[2];
  if (pair){
    cB[0] = make_float2( __shfl(cA[1].x, lx, 64), -__shfl(cA[1].y, lx, 64) );
    cB[1] = make_float2( __shfl(cA[0].x, lx, 64), -__shfl(cA[0].y, lx, 64) );
  }
  ifft128_wave(cA, l);
#pragma unroll
  for (int rr = 0; rr < 2; ++rr){
    int n1 = l + 64*rr;
    unsigned idx = (unsigned)n1 * (unsigned)k2A;       // < 131072
    float2 W = cmul(g_tw1024[idx >> 7], g_twf[idx & 127]);
    W.y = -W.y;
    rA[n1] = cmul(cA[rr], W);
  }
  if (pair){
    ifft128_wave(cB, l);
#pragma unroll
    for (int rr = 0; rr < 2; ++rr){
      int n1 = l + 64*rr;
      unsigned idx = (unsigned)n1 * (unsigned)k2B;     // <= 127*1023 < 131072
      float2 W = cmul(g_tw1024[idx >> 7], g_twf[idx & 127]);
      W.y = -W.y;
      rB[n1] = cmul(cB[rr], W);
    }
  }
}

// inv2: per n1, adjoint inverse 1024-pt FFT over K (storage order in, natural out);
// fused |rec - mix| reduction
extern "C" __global__ void __launch_bounds__(512) k_inv2(
    const float* __restrict__ mix, float2* __restrict__ buf, int row0){
  int wid = threadIdx.x >> 6, l = threadIdx.x & 63;
  int rl = blockIdx.y;
  int n1 = blockIdx.x*8 + wid;
  float2* rowp = buf + (size_t)rl*NFB;
  float2 v[16];
#pragma unroll
  for (int rr = 0; rr < 16; ++rr)
    v[rr] = rowp[(size_t)(rr*64 + l)*128 + n1];
  ifft1024_wave(v, l);
  const float* mr = mix + (size_t)(row0+rl)*TLEN;
  const float invn = 1.0f/(float)NFB;
  float acc = 0.f;
#pragma unroll
  for (int m = 0; m < 16; ++m){
    int n2 = l + 64*m;
    if (n2 < 500){
      int n = n1 + 128*n2;
      acc += fabsf(v[m].x*invn - mr[n]);
    }
  }
  acc = wred(acc);
  if (l == 0){
    int bank = (blockIdx.x*8 + wid + blockIdx.y*16) & 63;
    atomAddD(&g_part[bank][10], (double)acc);
  }
}

// ---------------- combine ----------------
extern "C" __global__ void __launch_bounds__(64) k_finalize(float* __restrict__ out){
  __shared__ double s[12];
  int t = threadIdx.x;
  if (t < 12){
    double v = 0.0;
    for (int b = 0; b < 64; ++b) v += g_part[b][t];
    s[t] = v;
  }
  __syncthreads();
  if (t == 0){
    double dt = s[0] / 4096000.0;
    double rt = s[1] / 4096000.0;
    double sp = s[2] / 4096000.0;
    double e0 = s[3] / 1024000.0, e1 = s[4] / 1024000.0;
    double e2 = s[5] / 1024000.0, e3 = s[6] / 1024000.0;
    double dec = fmax(e1 - 0.8*e0, 0.0) + fmax(e2 - 0.8*e1, 0.0) + fmax(e3 - 0.8*e2, 0.0);
    double c1 = 8240832.0;              // 64*513*251
    double freq = s[7]/c1 + 0.1*(1.0 - s[8]/c1);
    double mel  = s[9] / 1285120.0;     // 64*80*251
    double cons = s[10] / 4096000.0;
    double total = 3.0*(dt + 0.5*freq + 0.3*mel)
                 + (rt + 0.1*(sp + dec))
                 + 0.2*cons;
    out[0] = (float)total;
  }
}

extern "C" void kernel_launch(void* const* d_in, const int* in_sizes, int n_in,
                              void* d_out, int out_size, void* d_ws, size_t ws_size,
                              hipStream_t stream){
  const float* pd = (const float*)d_in[0];
  const float* pr = (const float*)d_in[1];
  const float* td = (const float*)d_in[2];
  const float* tr = (const float*)d_in[3];
  const float* mx = (const float*)d_in[4];
  float* out = (float*)d_out;
  float2* buf = (float2*)d_ws;

  size_t rowBytes = (size_t)NFB * sizeof(float2);     // 1 MiB per row
  int maxrows = (int)(ws_size / rowBytes);
  if (maxrows > ROWS) maxrows = ROWS;
  if (maxrows < 1) maxrows = 1;

  hipLaunchKernelGGL(k_init, dim3(4), dim3(256), 0, stream);
  hipLaunchKernelGGL(k_time, dim3(2048), dim3(256), 0, stream, pd, td, pr, tr);
  hipLaunchKernelGGL(k_stft, dim3(ROWS*NFR/4), dim3(256), 0, stream, pd, td);
  for (int row0 = 0; row0 < ROWS; row0 += maxrows){
    int nr = ROWS - row0; if (nr > maxrows) nr = maxrows;
    hipLaunchKernelGGL(k_fwd1, dim3(16, nr),  dim3(512), 0, stream, pd, pr, buf, row0);
    hipLaunchKernelGGL(k_mid,  dim3(129, nr), dim3(256), 0, stream, buf);
    hipLaunchKernelGGL(k_inv2, dim3(16, nr),  dim3(512), 0, stream, mx, buf, row0);
  }
  hipLaunchKernelGGL(k_finalize, dim3(1), dim3(64), 0, stream, out);
}